// Round 4
// baseline (182.333 us; speedup 1.0000x reference)
//
#include <hip/hip_runtime.h>

// SKA3D: x [B=2, C=64, D=64, H=64, W=64] fp32; w [B=2, G=8, 27, D, H, W] fp32
// out[b,c,d,h,w] = sum_k x[b,c,(d+di)%64,(h+hi)%64,(w+wi)%64] * w[b,c/8,k,d,h,w]
//
// R4: R3's single-wave d-sliding LDS ring, plus:
//  - w taps double-buffered in registers: wk(d+1) loaded during compute(d),
//    so the 27 HBM w-loads never stall first use (1 wave/SIMD -> 512 VGPR free)
//  - halo LDS reads are ds_read_b32 (not b128): row cost 12+5.8*2 vs 36 cyc
//  - explicit epilogue step: no dead STAGE(d0+9), no dead w prefetch
// Sync: single wave per block, no barriers, counted s_waitcnt vmcnt only.
// Per-iter VMEM ops: stage 12 + wk 27 + stores 8 = 47; at iter-d's wait the
// ops newer than wk(d) are stores(8)+stage(12)+wk_next(27)=47 -> vmcnt(47).

#define ND 64
#define NH 64
#define NW 64
#define HW 4096
#define DHW 262144
#define CPG 8

typedef const __attribute__((address_space(1))) unsigned int* gp_as1;
typedef __attribute__((address_space(3))) unsigned int* lp_as3;

__global__ __launch_bounds__(64, 1) void ska3d_kernel(const float* __restrict__ x,
                                                      const float* __restrict__ w,
                                                      float* __restrict__ out) {
    __shared__ float lds[4][CPG][6][NW];   // [slot][c][r][w] 48 KB

    const int lane = threadIdx.x;          // 0..63
    const int w0   = (lane & 15) * 4;      // w strip start
    const int hl   = lane >> 4;            // 0..3

    const int bid = blockIdx.x;
    const int dc  = bid & 7;               // d-chunk (8 planes each)
    const int ht  = (bid >> 3) & 15;       // h-tile (4 rows each)
    const int g   = (bid >> 7) & 7;
    const int b   = bid >> 10;

    const int d0 = dc * 8;
    const int h0 = ht * 4;
    const int h  = h0 + hl;

    const float* xb = x + (size_t)(b * 64 + g * CPG) * DHW;
    const float* wb = w + (size_t)(b * 8 + g) * 27 * DHW + h * NW + w0;
    float* ob = out + (size_t)(b * 64 + g * CPG) * DHW + h * NW + w0;

    const int wl = (w0 + 63) & 63;         // LDS index of x[w-1] (circular)
    const int wr = (w0 + 4) & 63;          // LDS index of x[w+4] (circular)

#define STAGE(p) do {                                                          \
        const int slot_ = (p) & 3;                                             \
        const int dd_   = (p) & 63;                                            \
        _Pragma("unroll")                                                      \
        for (int i = 0; i < 12; ++i) {                                         \
            const int fid = i * 64 + lane;     /* 16B unit id, 0..767 */       \
            const int c_  = fid / 96;                                          \
            const int rm_ = fid - c_ * 96;                                     \
            const int r_  = rm_ >> 4;          /* 0..5 */                      \
            const int ws_ = rm_ & 15;          /* 0..15 */                     \
            const int hh_ = (h0 - 1 + r_) & 63;                                \
            const float* gsrc = xb + (size_t)c_ * DHW + dd_ * HW + hh_ * NW + ws_ * 4; \
            __builtin_amdgcn_global_load_lds((gp_as1)gsrc,                     \
                (lp_as3)&lds[slot_][c_][r_][ws_ * 4], 16, 0, 0);               \
        }                                                                      \
    } while (0)

#define LOADW(arr, dp) do {                                                    \
        const float* wpn_ = wb + (size_t)(dp) * HW;                            \
        _Pragma("unroll")                                                      \
        for (int k = 0; k < 27; ++k)                                           \
            arr[k] = *(const float4*)(wpn_ + (size_t)k * DHW);                 \
    } while (0)

#define COMPUTE(d, WK) do {                                                    \
        float acc[CPG][4];                                                     \
        _Pragma("unroll")                                                      \
        for (int c = 0; c < CPG; ++c)                                          \
            acc[c][0] = acc[c][1] = acc[c][2] = acc[c][3] = 0.f;               \
        _Pragma("unroll")                                                      \
        for (int di = -1; di <= 1; ++di) {                                     \
            const int slot = ((d) + di) & 3;                                   \
            _Pragma("unroll")                                                  \
            for (int hi = -1; hi <= 1; ++hi) {                                 \
                const int r  = hl + hi + 1;                                    \
                const int kb = (di + 1) * 9 + (hi + 1) * 3;                    \
                _Pragma("unroll")                                              \
                for (int c = 0; c < CPG; ++c) {                                \
                    const float* row = &lds[slot][c][r][0];                    \
                    const float  xm = row[wl];                                 \
                    const float4 xv = *(const float4*)(row + w0);              \
                    const float  xp = row[wr];                                 \
                    const float4 wa = WK[kb], wm = WK[kb + 1], wc = WK[kb + 2];\
                    acc[c][0] += wa.x * xm;    acc[c][1] += wa.y * xv.x;       \
                    acc[c][2] += wa.z * xv.y;  acc[c][3] += wa.w * xv.z;       \
                    acc[c][0] += wm.x * xv.x;  acc[c][1] += wm.y * xv.y;       \
                    acc[c][2] += wm.z * xv.z;  acc[c][3] += wm.w * xv.w;       \
                    acc[c][0] += wc.x * xv.y;  acc[c][1] += wc.y * xv.z;       \
                    acc[c][2] += wc.z * xv.w;  acc[c][3] += wc.w * xp;         \
                }                                                              \
            }                                                                  \
        }                                                                      \
        _Pragma("unroll")                                                      \
        for (int c = 0; c < CPG; ++c)                                          \
            *(float4*)(ob + (size_t)c * DHW + (size_t)(d) * HW) =              \
                make_float4(acc[c][0], acc[c][1], acc[c][2], acc[c][3]);       \
    } while (0)

// full body: prefetch stage(d+2) + wk(d+1), drain stage(d+1)+wk(d), compute d
#define BODY(d, WC, WN) do {                                                   \
        STAGE((d) + 2);                                                        \
        LOADW(WN, (d) + 1);                                                    \
        asm volatile("s_waitcnt vmcnt(47)" ::: "memory");                      \
        COMPUTE((d), WC);                                                      \
    } while (0)

    float4 wkA[27], wkB[27];

    // prologue: planes d0-1, d0, d0+1; w taps for d0
    STAGE(d0 - 1);
    STAGE(d0);
    STAGE(d0 + 1);
    LOADW(wkA, d0);
    asm volatile("s_waitcnt vmcnt(0)" ::: "memory");

    // 7 full bodies (d0..d0+6), ping-pong A/B
#pragma unroll
    for (int i = 0; i < 3; ++i) {
        BODY(d0 + 2 * i,     wkA, wkB);
        BODY(d0 + 2 * i + 1, wkB, wkA);
    }
    BODY(d0 + 6, wkA, wkB);

    // epilogue d0+7: no stage, no prefetch; drain wk(d0+7): newer = stores(8)
    asm volatile("s_waitcnt vmcnt(8)" ::: "memory");
    COMPUTE(d0 + 7, wkB);
}

extern "C" void kernel_launch(void* const* d_in, const int* in_sizes, int n_in,
                              void* d_out, int out_size, void* d_ws, size_t ws_size,
                              hipStream_t stream) {
    const float* x = (const float*)d_in[0];
    const float* w = (const float*)d_in[1];
    float* out = (float*)d_out;
    // grid: b(2) x g(8) x h-tiles(16) x d-chunks(8) = 2048 single-wave blocks
    dim3 grid(2048);
    dim3 block(64);
    hipLaunchKernelGGL(ska3d_kernel, grid, block, 0, stream, x, w, out);
}

// Round 5
// 169.969 us; speedup vs baseline: 1.0727x; 1.0727x over previous
//
#include <hip/hip_runtime.h>

// SKA3D: x [B=2, C=64, D=64, H=64, W=64] fp32; w [B=2, G=8, 27, D, H, W] fp32
// out[b,c,d,h,w] = sum_k x[b,c,(d+di)%64,(h+hi)%64,(w+wi)%64] * w[b,c/8,k,d,h,w]
//
// R5: d-sliding LDS ring (4 slots x 8c x 6 rows x 64w = 48 KB) shared by a
// 256-thread block (4 waves, 2 channels per wave) -> 12 KB LDS per wave,
// 3 blocks/CU = 12 waves/CU (vs R3's 3). One raw s_barrier per iteration
// (no __syncthreads: avoids implicit vmcnt(0) drain). STAGE is issued AFTER
// the barrier so no wave can still be reading ring slot (d+2)&3 (WAR-safe by
// ordering, not timing). wk loads are per-wave redundant (4x, same addresses)
// -> served by L1/L2, no extra HBM.
//
// Per-wave per-iter VMEM: stage 3 + stores 2 + wk 27.
// Issue order: [A] vmcnt(29) drains my stage(d+1)  (newer: 2 stores + 27 wk)
//              [B] s_barrier   -> slot d+1 globally ready
//              [C] STAGE(d+2)  (3 ops)
//              [D] COMPUTE(d)  (2 float4 stores)
//              [E] LOADW(d+1)  (27 float4, consumed next iter)

#define ND 64
#define NH 64
#define NW 64
#define HW 4096
#define DHW 262144

typedef const __attribute__((address_space(1))) unsigned int* gp_as1;
typedef __attribute__((address_space(3))) unsigned int* lp_as3;

__global__ __launch_bounds__(256, 2) void ska3d_kernel(const float* __restrict__ x,
                                                       const float* __restrict__ w,
                                                       float* __restrict__ out) {
    __shared__ float lds[4][8][6][NW];     // [slot][c][r][w] 48 KB

    const int tid  = threadIdx.x;          // 0..255
    const int lane = tid & 63;
    const int wv   = tid >> 6;             // wave id 0..3
    const int w0   = (lane & 15) * 4;      // w strip start
    const int hl   = lane >> 4;            // 0..3
    const int c0   = wv * 2;               // this wave's channels: c0, c0+1

    const int bid = blockIdx.x;
    const int dc  = bid & 7;               // d-chunk (8 planes)
    const int ht  = (bid >> 3) & 15;       // h-tile (4 rows)
    const int g   = (bid >> 7) & 7;
    const int b   = bid >> 10;

    const int d0 = dc * 8;
    const int h0 = ht * 4;
    const int h  = h0 + hl;

    const float* xb = x + (size_t)(b * 64 + g * 8) * DHW;
    const float* wb = w + (size_t)(b * 8 + g) * 27 * DHW + h * NW + w0;
    float* ob = out + (size_t)(b * 64 + g * 8 + c0) * DHW + h * NW + w0;

    const int wl = (w0 + 63) & 63;         // LDS idx of x[w-1] (circular)
    const int wr = (w0 + 4) & 63;          // LDS idx of x[w+4] (circular)

    // stage plane p: 768 16B-units, 256 threads -> 3 ops/thread (per wave: 3)
#define STAGE(p) do {                                                          \
        const int slot_ = (p) & 3;                                             \
        const int dd_   = (p) & 63;                                            \
        _Pragma("unroll")                                                      \
        for (int i = 0; i < 3; ++i) {                                          \
            const int fid = i * 256 + tid;     /* 0..767 */                    \
            const int c_  = fid / 96;                                          \
            const int rm_ = fid - c_ * 96;                                     \
            const int r_  = rm_ >> 4;          /* 0..5 */                      \
            const int ws_ = rm_ & 15;          /* 0..15 */                     \
            const int hh_ = (h0 - 1 + r_) & 63;                                \
            const float* gsrc = xb + (size_t)c_ * DHW + dd_ * HW + hh_ * NW + ws_ * 4; \
            __builtin_amdgcn_global_load_lds((gp_as1)gsrc,                     \
                (lp_as3)&lds[slot_][c_][r_][ws_ * 4], 16, 0, 0);               \
        }                                                                      \
    } while (0)

#define LOADW(dp) do {                                                         \
        const float* wpn_ = wb + (size_t)(dp) * HW;                            \
        _Pragma("unroll")                                                      \
        for (int k = 0; k < 27; ++k)                                           \
            wk[k] = *(const float4*)(wpn_ + (size_t)k * DHW);                  \
    } while (0)

    float4 wk[27];

    // prologue: planes d0-1, d0, d0+1 staged; wk(d0) loaded; full drain
    STAGE(d0 - 1);
    STAGE(d0);
    STAGE(d0 + 1);
    LOADW(d0);
    asm volatile("s_waitcnt vmcnt(0)" ::: "memory");

#pragma unroll 1
    for (int i = 0; i < 8; ++i) {
        const int d = d0 + i;

        // [A] drain my stage(d+1); newer ops = 2 stores + 27 wk = 29
        asm volatile("s_waitcnt vmcnt(29)" ::: "memory");
        // [B] all waves' stage(d+1) done; also: all waves done reading (d-2)&3
        asm volatile("s_barrier" ::: "memory");

        // [C] prefetch plane d+2 into slot (d+2)&3 (disjoint from d-1,d,d+1)
        if (i < 7) STAGE(d + 2);

        // [D] compute d from LDS slots (d-1,d,d+1)&3 with wk(d) in registers
        float acc[2][4];
#pragma unroll
        for (int cc = 0; cc < 2; ++cc)
            acc[cc][0] = acc[cc][1] = acc[cc][2] = acc[cc][3] = 0.f;

#pragma unroll
        for (int di = -1; di <= 1; ++di) {
            const int slot = (d + di) & 3;
#pragma unroll
            for (int hi = -1; hi <= 1; ++hi) {
                const int r  = hl + hi + 1;            // 0..5
                const int kb = (di + 1) * 9 + (hi + 1) * 3;
#pragma unroll
                for (int cc = 0; cc < 2; ++cc) {
                    const float* row = &lds[slot][c0 + cc][r][0];
                    const float  xm = row[wl];
                    const float4 xv = *(const float4*)(row + w0);
                    const float  xp = row[wr];
                    const float4 wa = wk[kb], wm = wk[kb + 1], wc = wk[kb + 2];
                    acc[cc][0] += wa.x * xm;    acc[cc][1] += wa.y * xv.x;
                    acc[cc][2] += wa.z * xv.y;  acc[cc][3] += wa.w * xv.z;
                    acc[cc][0] += wm.x * xv.x;  acc[cc][1] += wm.y * xv.y;
                    acc[cc][2] += wm.z * xv.z;  acc[cc][3] += wm.w * xv.w;
                    acc[cc][0] += wc.x * xv.y;  acc[cc][1] += wc.y * xv.z;
                    acc[cc][2] += wc.z * xv.w;  acc[cc][3] += wc.w * xp;
                }
            }
        }

#pragma unroll
        for (int cc = 0; cc < 2; ++cc)
            *(float4*)(ob + (size_t)cc * DHW + (size_t)d * HW) =
                make_float4(acc[cc][0], acc[cc][1], acc[cc][2], acc[cc][3]);

        // [E] wk(d+1) for next iter (WAR on wk regs keeps it after COMPUTE)
        if (i < 7) LOADW(d + 1);
    }
}

extern "C" void kernel_launch(void* const* d_in, const int* in_sizes, int n_in,
                              void* d_out, int out_size, void* d_ws, size_t ws_size,
                              hipStream_t stream) {
    const float* x = (const float*)d_in[0];
    const float* w = (const float*)d_in[1];
    float* out = (float*)d_out;
    // grid: b(2) x g(8) x h-tiles(16) x d-chunks(8) = 2048 blocks of 256
    dim3 grid(2048);
    dim3 block(256);
    hipLaunchKernelGGL(ska3d_kernel, grid, block, 0, stream, x, w, out);
}